// Round 12
// baseline (401.667 us; speedup 1.0000x reference)
//
#include <hip/hip_runtime.h>
#include <math.h>

#define DD 64    // feature dim
#define APAD 512 // adj zero-pad (branch-free over-read)

typedef _Float16 h2 __attribute__((ext_vector_type(2)));
typedef _Float16 h4 __attribute__((ext_vector_type(4)));
typedef _Float16 h8 __attribute__((ext_vector_type(8)));
typedef float f32x4 __attribute__((ext_vector_type(4)));

// ---- fused one-time prep: W->MFMA frags | x->fp16 | degree hist ----
// blocks [0,wb): wconv (4 ids/block); [wb,wb+xb): xconv; [wb+xb,..): hist
__global__ __launch_bounds__(256) void k_prep(
    const float* __restrict__ Wq, const float* __restrict__ Wk,
    const float* __restrict__ Wv, const float* __restrict__ Ws,
    _Float16* __restrict__ wf,
    const float* __restrict__ x, _Float16* __restrict__ xb,
    const int* __restrict__ dst, int* __restrict__ deg,
    unsigned short* __restrict__ pos,
    int wb, int xb_, int total8, int ecnt)
{
  int tid = threadIdx.x;
  int bid = blockIdx.x;
  if (bid < wb) {
    int id = bid * 4 + (tid >> 6);  // layer*32 + c*2 + s
    int lane = tid & 63;
    int layer = id >> 5;
    int c = (id >> 1) & 15;
    int s = id & 1;
    int col = c * 16 + (lane & 15);
    int mi = col >> 6;
    const float* W = (mi == 0 ? Wq : mi == 1 ? Wk : mi == 2 ? Wv : Ws)
                     + (size_t)layer * DD * DD;
    int colw = col & 63;
    _Float16* o = wf + ((((size_t)(layer * 16 + c)) * 2 + s) * 64 + lane) * 8;
    #pragma unroll
    for (int j = 0; j < 8; ++j) {
      int k = s * 32 + (lane >> 4) * 8 + j;
      o[j] = (_Float16)W[k * DD + colw];
    }
  } else if (bid < wb + xb_) {
    int i = (bid - wb) * 256 + tid;
    if (i >= total8) return;
    float4 a = ((const float4*)x)[i * 2];
    float4 b = ((const float4*)x)[i * 2 + 1];
    h8 o;
    o[0] = (_Float16)a.x; o[1] = (_Float16)a.y; o[2] = (_Float16)a.z; o[3] = (_Float16)a.w;
    o[4] = (_Float16)b.x; o[5] = (_Float16)b.y; o[6] = (_Float16)b.z; o[7] = (_Float16)b.w;
    *(h8*)(xb + (size_t)i * 8) = o;
  } else {
    int e = ((bid - wb - xb_) * 256 + tid) * 4;
    if (e + 3 < ecnt) {
      int4 d = *(const int4*)(dst + e);
      pos[e]     = (unsigned short)atomicAdd(deg + d.x, 1);
      pos[e + 1] = (unsigned short)atomicAdd(deg + d.y, 1);
      pos[e + 2] = (unsigned short)atomicAdd(deg + d.z, 1);
      pos[e + 3] = (unsigned short)atomicAdd(deg + d.w, 1);
    } else {
      for (; e < ecnt; ++e)
        pos[e] = (unsigned short)atomicAdd(deg + dst[e], 1);
    }
  }
}

// ---- MFMA projection, swapped operands + per-wave LDS staging ----
#define LH_STRIDE 200   // halves per node row (192 used + 8 pad) = 400B
#define LS_STRIDE 72    // halves per node row (64 used + 8 pad)  = 144B
#define WAVE_LDS  (16 * 400 + 16 * 144)   // 8704B

__global__ __launch_bounds__(256) void k_projM(
    const _Float16* __restrict__ xb, const _Float16* __restrict__ wf,
    const float* __restrict__ bq, const float* __restrict__ bk,
    const float* __restrict__ bv, const float* __restrict__ bs,
    _Float16* __restrict__ qh, _Float16* __restrict__ kvh,
    _Float16* __restrict__ sh, int n)
{
  __shared__ __align__(16) char lds[4 * WAVE_LDS];
  int wave = threadIdx.x >> 6;
  int lane = threadIdx.x & 63;
  int nbase = blockIdx.x * 64 + wave * 16;
  if (nbase >= n) return;

  char* wbase = lds + wave * WAVE_LDS;
  _Float16* lh = (_Float16*)wbase;                 // [16][LH_STRIDE] QKV
  _Float16* ls = (_Float16*)(wbase + 16 * 400);    // [16][LS_STRIDE] S

  const int cl = lane & 15;
  const int rq = lane >> 4;

  int ar = min(nbase + cl, n - 1);
  h8 a0 = *(const h8*)(xb + (size_t)ar * DD + rq * 8);
  h8 a1 = *(const h8*)(xb + (size_t)ar * DD + 32 + rq * 8);

  #pragma unroll
  for (int c = 0; c < 16; ++c) {
    const float* bp = (c < 4) ? bq : (c < 8) ? bk : (c < 12) ? bv : bs;
    const int fb = c * 16 + rq * 4;          // global feature base (0..255)
    float4 b4 = *(const float4*)(bp + (fb & 63));
    f32x4 acc; acc[0] = b4.x; acc[1] = b4.y; acc[2] = b4.z; acc[3] = b4.w;
    const _Float16* wp = wf + ((size_t)(c * 2) * 64 + lane) * 8;
    h8 w0 = *(const h8*)(wp);
    h8 w1 = *(const h8*)(wp + 64 * 8);
    acc = __builtin_amdgcn_mfma_f32_16x16x32_f16(w0, a0, acc, 0, 0, 0);
    acc = __builtin_amdgcn_mfma_f32_16x16x32_f16(w1, a1, acc, 0, 0, 0);

    h4 o; o[0] = (_Float16)acc[0]; o[1] = (_Float16)acc[1];
    o[2] = (_Float16)acc[2]; o[3] = (_Float16)acc[3];
    if (c < 12)
      *(h4*)(lh + cl * LH_STRIDE + fb) = o;
    else
      *(h4*)(ls + cl * LS_STRIDE + (fb - 192)) = o;
  }

  // QH: 16 nodes x 128B
  #pragma unroll
  for (int i = 0; i < 2; ++i) {
    int chunk = i * 64 + lane;
    int nd = chunk >> 3, co = chunk & 7;
    h8 v = *(const h8*)(lh + nd * LH_STRIDE + co * 8);
    if (nbase + nd < n)
      *(h8*)(qh + (size_t)(nbase + nd) * DD + co * 8) = v;
  }
  // KVH: 16 nodes x 256B
  #pragma unroll
  for (int i = 0; i < 4; ++i) {
    int chunk = i * 64 + lane;
    int nd = chunk >> 4, co = chunk & 15;
    h8 v = *(const h8*)(lh + nd * LH_STRIDE + 64 + co * 8);
    if (nbase + nd < n)
      *(h8*)(kvh + (size_t)(nbase + nd) * 128 + co * 8) = v;
  }
  // S: 16 nodes x 128B fp16
  #pragma unroll
  for (int i = 0; i < 2; ++i) {
    int chunk = i * 64 + lane;
    int nd = chunk >> 3, co = chunk & 7;
    h8 v = *(const h8*)(ls + nd * LS_STRIDE + co * 8);
    if (nbase + nd < n)
      *(h8*)(sh + (size_t)(nbase + nd) * DD + co * 8) = v;
  }
}

// ---- parallel scan pass A: block-local scan + degree histogram (fused) ----
__global__ __launch_bounds__(1024) void k_scanA(
    const int* __restrict__ deg, int* __restrict__ rowptr,
    int* __restrict__ btot, int* __restrict__ dbins, int n)
{
  __shared__ int wsum[16];
  __shared__ int lbin[256];
  int tid = threadIdx.x;
  int lane = tid & 63, wave = tid >> 6;
  if (tid < 256) lbin[tid] = 0;
  __syncthreads();
  int i = blockIdx.x * 4096 + tid * 4;
  int4 d = make_int4(0, 0, 0, 0);
  if (i + 3 < n) d = *(const int4*)(deg + i);
  else {
    if (i     < n) d.x = deg[i];
    if (i + 1 < n) d.y = deg[i + 1];
    if (i + 2 < n) d.z = deg[i + 2];
  }
  if (i     < n) atomicAdd(&lbin[min(d.x, 255)], 1);
  if (i + 1 < n) atomicAdd(&lbin[min(d.y, 255)], 1);
  if (i + 2 < n) atomicAdd(&lbin[min(d.z, 255)], 1);
  if (i + 3 < n) atomicAdd(&lbin[min(d.w, 255)], 1);

  int s1 = d.x, s2 = s1 + d.y, s3 = s2 + d.z, s4 = s3 + d.w;
  int s = s4;
  #pragma unroll
  for (int off = 1; off < 64; off <<= 1) {
    int t = __shfl_up(s, off);
    if (lane >= off) s += t;
  }
  if (lane == 63) wsum[wave] = s;
  __syncthreads();
  if (wave == 0) {
    int ws = (lane < 16) ? wsum[lane] : 0;
    #pragma unroll
    for (int off = 1; off < 16; off <<= 1) {
      int t = __shfl_up(ws, off);
      if (lane >= off) ws += t;
    }
    if (lane < 16) wsum[lane] = ws;
  }
  __syncthreads();
  int excl = ((wave > 0) ? wsum[wave - 1] : 0) + s - s4;
  if (i     < n) rowptr[i + 1] = excl + s1;
  if (i + 1 < n) rowptr[i + 2] = excl + s2;
  if (i + 2 < n) rowptr[i + 3] = excl + s3;
  if (i + 3 < n) rowptr[i + 4] = excl + s4;
  if (tid == 0) {
    if (blockIdx.x == 0) rowptr[0] = 0;
    btot[blockIdx.x] = wsum[15];
  }
  if (tid < 256 && lbin[tid]) atomicAdd(&dbins[tid], lbin[tid]);
}

// ---- pass B: exclusive-scan block totals (<=64) AND 256 degree bins ----
__global__ __launch_bounds__(64) void k_scanB(
    int* __restrict__ btot, int nb, const int* __restrict__ dbins,
    int* __restrict__ dcur)
{
  int lane = threadIdx.x;
  int v = (lane < nb) ? btot[lane] : 0;
  int s = v;
  #pragma unroll
  for (int off = 1; off < 64; off <<= 1) {
    int t = __shfl_up(s, off);
    if (lane >= off) s += t;
  }
  if (lane < nb) btot[lane] = s - v;

  int4 dv = *(const int4*)(dbins + lane * 4);
  int t1 = dv.x, t2 = t1 + dv.y, t3 = t2 + dv.z, t4 = t3 + dv.w;
  int ss = t4;
  #pragma unroll
  for (int off = 1; off < 64; off <<= 1) {
    int t = __shfl_up(ss, off);
    if (lane >= off) ss += t;
  }
  int ex = ss - t4;
  dcur[lane * 4]     = ex;
  dcur[lane * 4 + 1] = ex + t1;
  dcur[lane * 4 + 2] = ex + t2;
  dcur[lane * 4 + 3] = ex + t3;
}

// ---- fused pass C (+block offsets) and counting-sort scatter (LPT order) ----
__global__ __launch_bounds__(1024) void k_scanCD(
    int* __restrict__ rowptr, const int* __restrict__ btot,
    const int* __restrict__ deg, int* __restrict__ dcur,
    int* __restrict__ order, int n, int nbk)
{
  __shared__ int lcnt[256];
  __shared__ int lbase[256];
  int tid = threadIdx.x;
  int b = blockIdx.x;
  if (b < nbk) {                      // scanC chunk
    int off = btot[b];
    if (off) {
      int i = b * 4096 + tid * 4;
      #pragma unroll
      for (int k = 1; k <= 4; ++k)
        if (i + k <= n) rowptr[i + k] += off;
    }
  }
  // dfill chunk
  if (tid < 256) lcnt[tid] = 0;
  __syncthreads();
  int i = b * 1024 + tid;
  int bin = 0, slot = 0;
  bool ok = (i < n);
  if (ok) {
    bin = min(deg[i], 255);
    slot = atomicAdd(&lcnt[bin], 1);
  }
  __syncthreads();
  if (tid < 256 && lcnt[tid]) lbase[tid] = atomicAdd(&dcur[tid], lcnt[tid]);
  __syncthreads();
  if (ok) order[(n - 1) - (lbase[bin] + slot)] = i;   // reversed = descending
}

// atomic-free CSR fill using precomputed pos
__global__ __launch_bounds__(256) void k_fill(
    const int* __restrict__ src, const int* __restrict__ dst,
    const int* __restrict__ rowptr, const unsigned short* __restrict__ pos,
    int* __restrict__ adj, int ecnt)
{
  int e = (blockIdx.x * 256 + threadIdx.x) * 4;
  if (e + 3 < ecnt) {
    int4 d = *(const int4*)(dst + e);
    int4 s = *(const int4*)(src + e);
    ushort4 p = *(const ushort4*)(pos + e);
    adj[rowptr[d.x] + p.x] = s.x;
    adj[rowptr[d.y] + p.y] = s.y;
    adj[rowptr[d.z] + p.z] = s.z;
    adj[rowptr[d.w] + p.w] = s.w;
  } else {
    for (; e < ecnt; ++e)
      adj[rowptr[dst[e]] + pos[e]] = src[e];
  }
}

#define H2OF(v, i) __builtin_shufflevector((v), (v), 2*(i), 2*(i)+1)

// ---- 8 nodes per wave, one 8-lane group per node (LPT degree order).
// Per-group loop (degree is group-uniform); exec mask handles divergence.
// Streaming data (order/Q/adj/S, XB/out stores) is non-temporal so L2
// retains the heavily-reused KV rows.
template<bool LAST>
__global__ __launch_bounds__(256) void k_node(
    const _Float16* __restrict__ qh, const _Float16* __restrict__ kvh,
    const int* __restrict__ rowptr, const int* __restrict__ adj,
    const int* __restrict__ order,
    const _Float16* __restrict__ sh, float* __restrict__ outp,
    _Float16* __restrict__ xbnext, int n)
{
  int wid = (blockIdx.x * blockDim.x + threadIdx.x) >> 6;
  int lane = threadIdx.x & 63;
  const int g = lane >> 3;   // node slot within wave
  const int t = lane & 7;    // dim-chunk (dims 8t..8t+7)

  int idx = wid * 8 + g;
  bool nok = (idx < n);
  int node = __builtin_nontemporal_load(order + (nok ? idx : (n - 1)));

  const h8 q8 = __builtin_nontemporal_load(
      (const h8*)(qh + (size_t)node * DD + t * 8));
  const h2 qp0 = H2OF(q8, 0), qp1 = H2OF(q8, 1), qp2 = H2OF(q8, 2), qp3 = H2OF(q8, 3);

  const int e0 = rowptr[node];
  const int d  = nok ? (rowptr[node + 1] - e0) : 0;

  float mg = -1e30f, den = 0.f;
  float agg[8] = {0.f, 0.f, 0.f, 0.f, 0.f, 0.f, 0.f, 0.f};

  const char* kvb = (const char*)kvh;
  const unsigned tb = (unsigned)t << 4;

  h8 kP, vP;
  {
    int s = __builtin_nontemporal_load(adj + e0);  // pad keeps this in-bounds
    unsigned off = ((unsigned)s << 8) + tb;
    kP = *(const h8*)(kvb + off);
    vP = *(const h8*)(kvb + off + 128);
  }

  for (int it = 0; it < d; ++it) {
    const h8 kc = kP, vc = vP;
    {                                   // prefetch next edge (over-reads ok)
      int s2 = __builtin_nontemporal_load(adj + e0 + it + 1);
      unsigned off = ((unsigned)s2 << 8) + tb;
      kP = *(const h8*)(kvb + off);
      vP = *(const h8*)(kvb + off + 128);
    }

#if __has_builtin(__builtin_amdgcn_fdot2)
    float p = __builtin_amdgcn_fdot2(qp0, H2OF(kc, 0), 0.f, false);
    p = __builtin_amdgcn_fdot2(qp1, H2OF(kc, 1), p, false);
    p = __builtin_amdgcn_fdot2(qp2, H2OF(kc, 2), p, false);
    p = __builtin_amdgcn_fdot2(qp3, H2OF(kc, 3), p, false);
#else
    h2 ph = qp0 * H2OF(kc, 0);
    ph = qp1 * H2OF(kc, 1) + ph;
    ph = qp2 * H2OF(kc, 2) + ph;
    ph = qp3 * H2OF(kc, 3) + ph;
    float p = (float)ph.x + (float)ph.y;
#endif
    p += __shfl_xor(p, 1);
    p += __shfl_xor(p, 2);
    p += __shfl_xor(p, 4);     // p replicated within the 8-lane group
    p *= 0.125f;               // 1/sqrt(64)

    if (p > mg) {              // group-uniform; first iter zeroes (exp(-1e30))
      float c = __expf(mg - p);
      den *= c;
      #pragma unroll
      for (int j = 0; j < 8; ++j) agg[j] *= c;
      mg = p;
    }
    float w = __expf(p - mg);
    den += w;
    #pragma unroll
    for (int j = 0; j < 8; ++j)
      agg[j] = fmaf(w, (float)vc[j], agg[j]);
  }

  if (nok) {
    float inv = (den > 0.f) ? (1.0f / den) : 0.f;
    const h8 s8 = __builtin_nontemporal_load(
        (const h8*)(sh + (size_t)node * DD + t * 8));
    float r[8];
    #pragma unroll
    for (int j = 0; j < 8; ++j)
      r[j] = fmaxf(fmaf(agg[j], inv, (float)s8[j]), 0.f);
    if (LAST) {
      float* op = outp + (size_t)node * DD + t * 8;
      f32x4 ra; ra[0] = r[0]; ra[1] = r[1]; ra[2] = r[2]; ra[3] = r[3];
      f32x4 rb; rb[0] = r[4]; rb[1] = r[5]; rb[2] = r[6]; rb[3] = r[7];
      __builtin_nontemporal_store(ra, (f32x4*)(op));
      __builtin_nontemporal_store(rb, (f32x4*)(op + 4));
    } else {
      h8 xh;
      #pragma unroll
      for (int j = 0; j < 8; ++j) xh[j] = (_Float16)r[j];
      __builtin_nontemporal_store(xh, (h8*)(xbnext + (size_t)node * DD + t * 8));
    }
  }
}

// batch is sorted: run-length accumulate per wave, flush on graph change
__global__ __launch_bounds__(64) void k_pool_sum(
    const float* __restrict__ x, const int* __restrict__ batch,
    float* __restrict__ gsum, int n)
{
  int lane = threadIdx.x;
  int n0 = blockIdx.x * 64;
  if (n0 >= n) return;
  int n1 = min(n0 + 64, n);
  float acc = 0.f;
  int g_prev = batch[n0];
  for (int nn = n0; nn < n1; ++nn) {
    int g = batch[nn];
    if (g != g_prev) {
      atomicAdd(gsum + (size_t)g_prev * DD + lane, acc);
      acc = 0.f; g_prev = g;
    }
    acc += __builtin_nontemporal_load(x + (size_t)nn * DD + lane);
  }
  atomicAdd(gsum + (size_t)g_prev * DD + lane, acc);
}

__device__ __forceinline__ int lbound(const int* __restrict__ a, int n, int key)
{
  int lo = 0, hi = n;
  while (lo < hi) {
    int mid = (lo + hi) >> 1;
    if (a[mid] < key) lo = mid + 1; else hi = mid;
  }
  return lo;
}

// emb = gsum / count(g); counts via binary search on sorted batch
__global__ __launch_bounds__(256) void k_pool_div(
    const float* __restrict__ gsum, const int* __restrict__ batch,
    float* __restrict__ emb, int gtot, int n)
{
  int gid = blockIdx.x * blockDim.x + threadIdx.x;
  if (gid >= gtot * DD) return;
  int g = gid >> 6;
  int cnt = lbound(batch, n, g + 1) - lbound(batch, n, g);
  emb[gid] = gsum[gid] / fmaxf((float)cnt, 1.0f);
}

extern "C" void kernel_launch(void* const* d_in, const int* in_sizes, int n_in,
                              void* d_out, int out_size, void* d_ws, size_t ws_size,
                              hipStream_t stream)
{
  const float* x_in  = (const float*)d_in[0];
  const int*   ei    = (const int*)  d_in[1];
  const int*   batch = (const int*)  d_in[2];
  const float* Wq = (const float*)d_in[3];
  const float* bq = (const float*)d_in[4];
  const float* Wk = (const float*)d_in[5];
  const float* bk = (const float*)d_in[6];
  const float* Wv = (const float*)d_in[7];
  const float* bv = (const float*)d_in[8];
  const float* Ws = (const float*)d_in[9];
  const float* bs = (const float*)d_in[10];

  const int nd     = in_sizes[0];             // N*D
  const int n      = nd / DD;                 // N
  const int ecnt   = in_sizes[1] / 2;         // E
  const int layers = in_sizes[3] / (DD * DD); // L
  const int gtot   = (out_size - nd) / DD;    // G

  const int* src = ei;
  const int* dst = ei + ecnt;

  // workspace layout: adj pad, deg, dbins, gsum contiguous -> ONE memset
  char* cur = (char*)d_ws;
  _Float16*  SH  = (_Float16*)cur;  cur += (size_t)nd * 2;        // fp16 skip S
  _Float16*  XB  = (_Float16*)cur;  cur += (size_t)nd * 2;        // fp16 x
  _Float16*  QH  = (_Float16*)cur;  cur += (size_t)nd * 2;        // fp16 Q
  _Float16*  KVH = (_Float16*)cur;  cur += (size_t)nd * 4;        // fp16 K|V
  _Float16*  WF  = (_Float16*)cur;  cur += (size_t)layers * 16384 * 2; // W frags
  int* rowptr = (int*)cur;          cur += (size_t)(n + 4) * 4;
  int* adj    = (int*)cur;          cur += (size_t)(ecnt + APAD) * 4;
  int* deg    = (int*)cur;          cur += (size_t)n * 4;
  int* dbins  = (int*)cur;          cur += 256 * 4;
  float* gsum = (float*)cur;        cur += (size_t)gtot * DD * 4;
  int* dcur   = (int*)cur;          cur += 256 * 4;
  int* btot   = (int*)cur;          cur += 64 * 4;
  int* order  = (int*)cur;          cur += (size_t)n * 4;
  unsigned short* pos = (unsigned short*)cur; cur += (size_t)ecnt * 2;

  float* out = (float*)d_out;

  // ---- one memset covers adj pad + deg + dbins + gsum ----
  hipMemsetAsync(adj + ecnt, 0,
                 (size_t)(APAD + n + 256 + gtot * DD) * 4, stream);

  // ---- fused prep: W frags | x fp16 | degree hist ----
  const int wb  = layers * 8;
  const int xbk = (n * 8 + 255) / 256;
  const int hbk = (ecnt + 1023) / 1024;
  k_prep<<<wb + xbk + hbk, 256, 0, stream>>>(Wq, Wk, Wv, Ws, WF,
                                             x_in, XB, dst, deg, pos,
                                             wb, xbk, n * 8, ecnt);
  const int nbk = (n + 4095) / 4096;
  k_scanA<<<nbk, 1024, 0, stream>>>(deg, rowptr, btot, dbins, n);
  k_scanB<<<1, 64, 0, stream>>>(btot, nbk, dbins, dcur);
  const int dblk = (n + 1023) / 1024;
  k_scanCD<<<dblk, 1024, 0, stream>>>(rowptr, btot, deg, dcur, order, n, nbk);
  k_fill<<<hbk, 256, 0, stream>>>(src, dst, rowptr, pos, adj, ecnt);

  const int pj = (n + 63) / 64;
  const int nb = (n + 31) / 32;   // 8 nodes/wave, 4 waves/block

  for (int l = 0; l < layers; ++l) {
    const size_t bo = (size_t)l * DD;
    k_projM<<<pj, 256, 0, stream>>>(XB, WF + (size_t)l * 16384,
                                    bq + bo, bk + bo, bv + bo, bs + bo,
                                    QH, KVH, SH, n);
    if (l == layers - 1)
      k_node<true><<<nb, 256, 0, stream>>>(QH, KVH, rowptr, adj, order,
                                           SH, out, XB, n);
    else
      k_node<false><<<nb, 256, 0, stream>>>(QH, KVH, rowptr, adj, order,
                                            SH, out, XB, n);
  }

  const int pbk = (n + 63) / 64;
  k_pool_sum<<<pbk, 64, 0, stream>>>(out, batch, gsum, n);
  const int fb = (gtot * DD + 255) / 256;
  k_pool_div<<<fb, 256, 0, stream>>>(gsum, batch, out + (size_t)nd, gtot, n);
}

// Round 13
// 334.521 us; speedup vs baseline: 1.2007x; 1.2007x over previous
//
#include <hip/hip_runtime.h>
#include <math.h>

#define DD 64    // feature dim
#define APAD 512 // adj zero-pad (branch-free over-read)

typedef _Float16 h2 __attribute__((ext_vector_type(2)));
typedef _Float16 h4 __attribute__((ext_vector_type(4)));
typedef _Float16 h8 __attribute__((ext_vector_type(8)));
typedef float f32x4 __attribute__((ext_vector_type(4)));

// ---- fused one-time prep: W->MFMA frags | x->fp16 | degree hist ----
// blocks [0,wb): wconv (4 ids/block); [wb,wb+xb): xconv; [wb+xb,..): hist
__global__ __launch_bounds__(256) void k_prep(
    const float* __restrict__ Wq, const float* __restrict__ Wk,
    const float* __restrict__ Wv, const float* __restrict__ Ws,
    _Float16* __restrict__ wf,
    const float* __restrict__ x, _Float16* __restrict__ xb,
    const int* __restrict__ dst, int* __restrict__ deg,
    unsigned short* __restrict__ pos,
    int wb, int xb_, int total8, int ecnt)
{
  int tid = threadIdx.x;
  int bid = blockIdx.x;
  if (bid < wb) {
    int id = bid * 4 + (tid >> 6);  // layer*32 + c*2 + s
    int lane = tid & 63;
    int layer = id >> 5;
    int c = (id >> 1) & 15;
    int s = id & 1;
    int col = c * 16 + (lane & 15);
    int mi = col >> 6;
    const float* W = (mi == 0 ? Wq : mi == 1 ? Wk : mi == 2 ? Wv : Ws)
                     + (size_t)layer * DD * DD;
    int colw = col & 63;
    _Float16* o = wf + ((((size_t)(layer * 16 + c)) * 2 + s) * 64 + lane) * 8;
    #pragma unroll
    for (int j = 0; j < 8; ++j) {
      int k = s * 32 + (lane >> 4) * 8 + j;
      o[j] = (_Float16)W[k * DD + colw];
    }
  } else if (bid < wb + xb_) {
    int i = (bid - wb) * 256 + tid;
    if (i >= total8) return;
    float4 a = ((const float4*)x)[i * 2];
    float4 b = ((const float4*)x)[i * 2 + 1];
    h8 o;
    o[0] = (_Float16)a.x; o[1] = (_Float16)a.y; o[2] = (_Float16)a.z; o[3] = (_Float16)a.w;
    o[4] = (_Float16)b.x; o[5] = (_Float16)b.y; o[6] = (_Float16)b.z; o[7] = (_Float16)b.w;
    *(h8*)(xb + (size_t)i * 8) = o;
  } else {
    int e = ((bid - wb - xb_) * 256 + tid) * 4;
    if (e + 3 < ecnt) {
      int4 d = *(const int4*)(dst + e);
      pos[e]     = (unsigned short)atomicAdd(deg + d.x, 1);
      pos[e + 1] = (unsigned short)atomicAdd(deg + d.y, 1);
      pos[e + 2] = (unsigned short)atomicAdd(deg + d.z, 1);
      pos[e + 3] = (unsigned short)atomicAdd(deg + d.w, 1);
    } else {
      for (; e < ecnt; ++e)
        pos[e] = (unsigned short)atomicAdd(deg + dst[e], 1);
    }
  }
}

// ---- MFMA projection, swapped operands + per-wave LDS staging ----
#define LH_STRIDE 200   // halves per node row (192 used + 8 pad) = 400B
#define LS_STRIDE 72    // halves per node row (64 used + 8 pad)  = 144B
#define WAVE_LDS  (16 * 400 + 16 * 144)   // 8704B

__global__ __launch_bounds__(256) void k_projM(
    const _Float16* __restrict__ xb, const _Float16* __restrict__ wf,
    const float* __restrict__ bq, const float* __restrict__ bk,
    const float* __restrict__ bv, const float* __restrict__ bs,
    _Float16* __restrict__ qh, _Float16* __restrict__ kvh,
    _Float16* __restrict__ sh, int n)
{
  __shared__ __align__(16) char lds[4 * WAVE_LDS];
  int wave = threadIdx.x >> 6;
  int lane = threadIdx.x & 63;
  int nbase = blockIdx.x * 64 + wave * 16;
  if (nbase >= n) return;

  char* wbase = lds + wave * WAVE_LDS;
  _Float16* lh = (_Float16*)wbase;                 // [16][LH_STRIDE] QKV
  _Float16* ls = (_Float16*)(wbase + 16 * 400);    // [16][LS_STRIDE] S

  const int cl = lane & 15;
  const int rq = lane >> 4;

  int ar = min(nbase + cl, n - 1);
  h8 a0 = *(const h8*)(xb + (size_t)ar * DD + rq * 8);
  h8 a1 = *(const h8*)(xb + (size_t)ar * DD + 32 + rq * 8);

  #pragma unroll
  for (int c = 0; c < 16; ++c) {
    const float* bp = (c < 4) ? bq : (c < 8) ? bk : (c < 12) ? bv : bs;
    const int fb = c * 16 + rq * 4;          // global feature base (0..255)
    float4 b4 = *(const float4*)(bp + (fb & 63));
    f32x4 acc; acc[0] = b4.x; acc[1] = b4.y; acc[2] = b4.z; acc[3] = b4.w;
    const _Float16* wp = wf + ((size_t)(c * 2) * 64 + lane) * 8;
    h8 w0 = *(const h8*)(wp);
    h8 w1 = *(const h8*)(wp + 64 * 8);
    acc = __builtin_amdgcn_mfma_f32_16x16x32_f16(w0, a0, acc, 0, 0, 0);
    acc = __builtin_amdgcn_mfma_f32_16x16x32_f16(w1, a1, acc, 0, 0, 0);

    h4 o; o[0] = (_Float16)acc[0]; o[1] = (_Float16)acc[1];
    o[2] = (_Float16)acc[2]; o[3] = (_Float16)acc[3];
    if (c < 12)
      *(h4*)(lh + cl * LH_STRIDE + fb) = o;
    else
      *(h4*)(ls + cl * LS_STRIDE + (fb - 192)) = o;
  }

  // QH: 16 nodes x 128B
  #pragma unroll
  for (int i = 0; i < 2; ++i) {
    int chunk = i * 64 + lane;
    int nd = chunk >> 3, co = chunk & 7;
    h8 v = *(const h8*)(lh + nd * LH_STRIDE + co * 8);
    if (nbase + nd < n)
      *(h8*)(qh + (size_t)(nbase + nd) * DD + co * 8) = v;
  }
  // KVH: 16 nodes x 256B
  #pragma unroll
  for (int i = 0; i < 4; ++i) {
    int chunk = i * 64 + lane;
    int nd = chunk >> 4, co = chunk & 15;
    h8 v = *(const h8*)(lh + nd * LH_STRIDE + 64 + co * 8);
    if (nbase + nd < n)
      *(h8*)(kvh + (size_t)(nbase + nd) * 128 + co * 8) = v;
  }
  // S: 16 nodes x 128B fp16
  #pragma unroll
  for (int i = 0; i < 2; ++i) {
    int chunk = i * 64 + lane;
    int nd = chunk >> 3, co = chunk & 7;
    h8 v = *(const h8*)(ls + nd * LS_STRIDE + co * 8);
    if (nbase + nd < n)
      *(h8*)(sh + (size_t)(nbase + nd) * DD + co * 8) = v;
  }
}

// ---- parallel scan pass A: block-local scan + degree histogram (fused) ----
__global__ __launch_bounds__(1024) void k_scanA(
    const int* __restrict__ deg, int* __restrict__ rowptr,
    int* __restrict__ btot, int* __restrict__ dbins, int n)
{
  __shared__ int wsum[16];
  __shared__ int lbin[256];
  int tid = threadIdx.x;
  int lane = tid & 63, wave = tid >> 6;
  if (tid < 256) lbin[tid] = 0;
  __syncthreads();
  int i = blockIdx.x * 4096 + tid * 4;
  int4 d = make_int4(0, 0, 0, 0);
  if (i + 3 < n) d = *(const int4*)(deg + i);
  else {
    if (i     < n) d.x = deg[i];
    if (i + 1 < n) d.y = deg[i + 1];
    if (i + 2 < n) d.z = deg[i + 2];
  }
  if (i     < n) atomicAdd(&lbin[min(d.x, 255)], 1);
  if (i + 1 < n) atomicAdd(&lbin[min(d.y, 255)], 1);
  if (i + 2 < n) atomicAdd(&lbin[min(d.z, 255)], 1);
  if (i + 3 < n) atomicAdd(&lbin[min(d.w, 255)], 1);

  int s1 = d.x, s2 = s1 + d.y, s3 = s2 + d.z, s4 = s3 + d.w;
  int s = s4;
  #pragma unroll
  for (int off = 1; off < 64; off <<= 1) {
    int t = __shfl_up(s, off);
    if (lane >= off) s += t;
  }
  if (lane == 63) wsum[wave] = s;
  __syncthreads();
  if (wave == 0) {
    int ws = (lane < 16) ? wsum[lane] : 0;
    #pragma unroll
    for (int off = 1; off < 16; off <<= 1) {
      int t = __shfl_up(ws, off);
      if (lane >= off) ws += t;
    }
    if (lane < 16) wsum[lane] = ws;
  }
  __syncthreads();
  int excl = ((wave > 0) ? wsum[wave - 1] : 0) + s - s4;
  if (i     < n) rowptr[i + 1] = excl + s1;
  if (i + 1 < n) rowptr[i + 2] = excl + s2;
  if (i + 2 < n) rowptr[i + 3] = excl + s3;
  if (i + 3 < n) rowptr[i + 4] = excl + s4;
  if (tid == 0) {
    if (blockIdx.x == 0) rowptr[0] = 0;
    btot[blockIdx.x] = wsum[15];
  }
  if (tid < 256 && lbin[tid]) atomicAdd(&dbins[tid], lbin[tid]);
}

// ---- pass B: exclusive-scan block totals (<=64) AND 256 degree bins ----
__global__ __launch_bounds__(64) void k_scanB(
    int* __restrict__ btot, int nb, const int* __restrict__ dbins,
    int* __restrict__ dcur)
{
  int lane = threadIdx.x;
  int v = (lane < nb) ? btot[lane] : 0;
  int s = v;
  #pragma unroll
  for (int off = 1; off < 64; off <<= 1) {
    int t = __shfl_up(s, off);
    if (lane >= off) s += t;
  }
  if (lane < nb) btot[lane] = s - v;

  int4 dv = *(const int4*)(dbins + lane * 4);
  int t1 = dv.x, t2 = t1 + dv.y, t3 = t2 + dv.z, t4 = t3 + dv.w;
  int ss = t4;
  #pragma unroll
  for (int off = 1; off < 64; off <<= 1) {
    int t = __shfl_up(ss, off);
    if (lane >= off) ss += t;
  }
  int ex = ss - t4;
  dcur[lane * 4]     = ex;
  dcur[lane * 4 + 1] = ex + t1;
  dcur[lane * 4 + 2] = ex + t2;
  dcur[lane * 4 + 3] = ex + t3;
}

// ---- fused pass C (+block offsets) and counting-sort scatter (LPT order) ----
__global__ __launch_bounds__(1024) void k_scanCD(
    int* __restrict__ rowptr, const int* __restrict__ btot,
    const int* __restrict__ deg, int* __restrict__ dcur,
    int* __restrict__ order, int n, int nbk)
{
  __shared__ int lcnt[256];
  __shared__ int lbase[256];
  int tid = threadIdx.x;
  int b = blockIdx.x;
  if (b < nbk) {                      // scanC chunk
    int off = btot[b];
    if (off) {
      int i = b * 4096 + tid * 4;
      #pragma unroll
      for (int k = 1; k <= 4; ++k)
        if (i + k <= n) rowptr[i + k] += off;
    }
  }
  // dfill chunk
  if (tid < 256) lcnt[tid] = 0;
  __syncthreads();
  int i = b * 1024 + tid;
  int bin = 0, slot = 0;
  bool ok = (i < n);
  if (ok) {
    bin = min(deg[i], 255);
    slot = atomicAdd(&lcnt[bin], 1);
  }
  __syncthreads();
  if (tid < 256 && lcnt[tid]) lbase[tid] = atomicAdd(&dcur[tid], lcnt[tid]);
  __syncthreads();
  if (ok) order[(n - 1) - (lbase[bin] + slot)] = i;   // reversed = descending
}

// atomic-free CSR fill using precomputed pos
__global__ __launch_bounds__(256) void k_fill(
    const int* __restrict__ src, const int* __restrict__ dst,
    const int* __restrict__ rowptr, const unsigned short* __restrict__ pos,
    int* __restrict__ adj, int ecnt)
{
  int e = (blockIdx.x * 256 + threadIdx.x) * 4;
  if (e + 3 < ecnt) {
    int4 d = *(const int4*)(dst + e);
    int4 s = *(const int4*)(src + e);
    ushort4 p = *(const ushort4*)(pos + e);
    adj[rowptr[d.x] + p.x] = s.x;
    adj[rowptr[d.y] + p.y] = s.y;
    adj[rowptr[d.z] + p.z] = s.z;
    adj[rowptr[d.w] + p.w] = s.w;
  } else {
    for (; e < ecnt; ++e)
      adj[rowptr[dst[e]] + pos[e]] = src[e];
  }
}

#define H2OF(v, i) __builtin_shufflevector((v), (v), 2*(i), 2*(i)+1)

// ---- 8 nodes per wave, one 8-lane group per node (LPT degree order).
// Per-group loop (degree is group-uniform); exec mask handles divergence.
template<bool LAST>
__global__ __launch_bounds__(256) void k_node(
    const _Float16* __restrict__ qh, const _Float16* __restrict__ kvh,
    const int* __restrict__ rowptr, const int* __restrict__ adj,
    const int* __restrict__ order,
    const _Float16* __restrict__ sh, float* __restrict__ outp,
    _Float16* __restrict__ xbnext, int n)
{
  int wid = (blockIdx.x * blockDim.x + threadIdx.x) >> 6;
  int lane = threadIdx.x & 63;
  const int g = lane >> 3;   // node slot within wave
  const int t = lane & 7;    // dim-chunk (dims 8t..8t+7)

  int idx = wid * 8 + g;
  bool nok = (idx < n);
  int node = order[nok ? idx : (n - 1)];

  const h8 q8 = *(const h8*)(qh + (size_t)node * DD + t * 8);
  const h2 qp0 = H2OF(q8, 0), qp1 = H2OF(q8, 1), qp2 = H2OF(q8, 2), qp3 = H2OF(q8, 3);

  const int e0 = rowptr[node];
  const int d  = nok ? (rowptr[node + 1] - e0) : 0;

  float mg = -1e30f, den = 0.f;
  float agg[8] = {0.f, 0.f, 0.f, 0.f, 0.f, 0.f, 0.f, 0.f};

  const char* kvb = (const char*)kvh;
  const unsigned tb = (unsigned)t << 4;

  h8 kP, vP;
  {
    int s = adj[e0];                    // pad keeps this in-bounds
    unsigned off = ((unsigned)s << 8) + tb;
    kP = *(const h8*)(kvb + off);
    vP = *(const h8*)(kvb + off + 128);
  }

  for (int it = 0; it < d; ++it) {
    const h8 kc = kP, vc = vP;
    {                                   // prefetch next edge (over-reads pad)
      int s2 = adj[e0 + it + 1];
      unsigned off = ((unsigned)s2 << 8) + tb;
      kP = *(const h8*)(kvb + off);
      vP = *(const h8*)(kvb + off + 128);
    }

#if __has_builtin(__builtin_amdgcn_fdot2)
    float p = __builtin_amdgcn_fdot2(qp0, H2OF(kc, 0), 0.f, false);
    p = __builtin_amdgcn_fdot2(qp1, H2OF(kc, 1), p, false);
    p = __builtin_amdgcn_fdot2(qp2, H2OF(kc, 2), p, false);
    p = __builtin_amdgcn_fdot2(qp3, H2OF(kc, 3), p, false);
#else
    h2 ph = qp0 * H2OF(kc, 0);
    ph = qp1 * H2OF(kc, 1) + ph;
    ph = qp2 * H2OF(kc, 2) + ph;
    ph = qp3 * H2OF(kc, 3) + ph;
    float p = (float)ph.x + (float)ph.y;
#endif
    p += __shfl_xor(p, 1);
    p += __shfl_xor(p, 2);
    p += __shfl_xor(p, 4);     // p replicated within the 8-lane group
    p *= 0.125f;               // 1/sqrt(64)

    if (p > mg) {              // group-uniform; first iter rescales by 0
      float c = __expf(mg - p);
      den *= c;
      #pragma unroll
      for (int j = 0; j < 8; ++j) agg[j] *= c;
      mg = p;
    }
    float w = __expf(p - mg);
    den += w;
    #pragma unroll
    for (int j = 0; j < 8; ++j)
      agg[j] = fmaf(w, (float)vc[j], agg[j]);
  }

  if (nok) {
    float inv = (den > 0.f) ? (1.0f / den) : 0.f;
    const h8 s8 = *(const h8*)(sh + (size_t)node * DD + t * 8);
    float r[8];
    #pragma unroll
    for (int j = 0; j < 8; ++j)
      r[j] = fmaxf(fmaf(agg[j], inv, (float)s8[j]), 0.f);
    if (LAST) {
      float* op = outp + (size_t)node * DD + t * 8;
      *(float4*)(op)     = make_float4(r[0], r[1], r[2], r[3]);
      *(float4*)(op + 4) = make_float4(r[4], r[5], r[6], r[7]);
    } else {
      h8 xh;
      #pragma unroll
      for (int j = 0; j < 8; ++j) xh[j] = (_Float16)r[j];
      *(h8*)(xbnext + (size_t)node * DD + t * 8) = xh;
    }
  }
}

// batch is sorted: run-length accumulate per wave, flush on graph change
__global__ __launch_bounds__(64) void k_pool_sum(
    const float* __restrict__ x, const int* __restrict__ batch,
    float* __restrict__ gsum, int n)
{
  int lane = threadIdx.x;
  int n0 = blockIdx.x * 64;
  if (n0 >= n) return;
  int n1 = min(n0 + 64, n);
  float acc = 0.f;
  int g_prev = batch[n0];
  for (int nn = n0; nn < n1; ++nn) {
    int g = batch[nn];
    if (g != g_prev) {
      atomicAdd(gsum + (size_t)g_prev * DD + lane, acc);
      acc = 0.f; g_prev = g;
    }
    acc += x[(size_t)nn * DD + lane];
  }
  atomicAdd(gsum + (size_t)g_prev * DD + lane, acc);
}

__device__ __forceinline__ int lbound(const int* __restrict__ a, int n, int key)
{
  int lo = 0, hi = n;
  while (lo < hi) {
    int mid = (lo + hi) >> 1;
    if (a[mid] < key) lo = mid + 1; else hi = mid;
  }
  return lo;
}

// emb = gsum / count(g); counts via binary search on sorted batch
__global__ __launch_bounds__(256) void k_pool_div(
    const float* __restrict__ gsum, const int* __restrict__ batch,
    float* __restrict__ emb, int gtot, int n)
{
  int gid = blockIdx.x * blockDim.x + threadIdx.x;
  if (gid >= gtot * DD) return;
  int g = gid >> 6;
  int cnt = lbound(batch, n, g + 1) - lbound(batch, n, g);
  emb[gid] = gsum[gid] / fmaxf((float)cnt, 1.0f);
}

extern "C" void kernel_launch(void* const* d_in, const int* in_sizes, int n_in,
                              void* d_out, int out_size, void* d_ws, size_t ws_size,
                              hipStream_t stream)
{
  const float* x_in  = (const float*)d_in[0];
  const int*   ei    = (const int*)  d_in[1];
  const int*   batch = (const int*)  d_in[2];
  const float* Wq = (const float*)d_in[3];
  const float* bq = (const float*)d_in[4];
  const float* Wk = (const float*)d_in[5];
  const float* bk = (const float*)d_in[6];
  const float* Wv = (const float*)d_in[7];
  const float* bv = (const float*)d_in[8];
  const float* Ws = (const float*)d_in[9];
  const float* bs = (const float*)d_in[10];

  const int nd     = in_sizes[0];             // N*D
  const int n      = nd / DD;                 // N
  const int ecnt   = in_sizes[1] / 2;         // E
  const int layers = in_sizes[3] / (DD * DD); // L
  const int gtot   = (out_size - nd) / DD;    // G

  const int* src = ei;
  const int* dst = ei + ecnt;

  // workspace layout: adj pad, deg, dbins, gsum contiguous -> ONE memset
  char* cur = (char*)d_ws;
  _Float16*  SH  = (_Float16*)cur;  cur += (size_t)nd * 2;        // fp16 skip S
  _Float16*  XB  = (_Float16*)cur;  cur += (size_t)nd * 2;        // fp16 x
  _Float16*  QH  = (_Float16*)cur;  cur += (size_t)nd * 2;        // fp16 Q
  _Float16*  KVH = (_Float16*)cur;  cur += (size_t)nd * 4;        // fp16 K|V
  _Float16*  WF  = (_Float16*)cur;  cur += (size_t)layers * 16384 * 2; // W frags
  int* rowptr = (int*)cur;          cur += (size_t)(n + 4) * 4;
  int* adj    = (int*)cur;          cur += (size_t)(ecnt + APAD) * 4;
  int* deg    = (int*)cur;          cur += (size_t)n * 4;
  int* dbins  = (int*)cur;          cur += 256 * 4;
  float* gsum = (float*)cur;        cur += (size_t)gtot * DD * 4;
  int* dcur   = (int*)cur;          cur += 256 * 4;
  int* btot   = (int*)cur;          cur += 64 * 4;
  int* order  = (int*)cur;          cur += (size_t)n * 4;
  unsigned short* pos = (unsigned short*)cur; cur += (size_t)ecnt * 2;

  float* out = (float*)d_out;

  // ---- one memset covers adj pad + deg + dbins + gsum ----
  hipMemsetAsync(adj + ecnt, 0,
                 (size_t)(APAD + n + 256 + gtot * DD) * 4, stream);

  // ---- fused prep: W frags | x fp16 | degree hist ----
  const int wb  = layers * 8;
  const int xbk = (n * 8 + 255) / 256;
  const int hbk = (ecnt + 1023) / 1024;
  k_prep<<<wb + xbk + hbk, 256, 0, stream>>>(Wq, Wk, Wv, Ws, WF,
                                             x_in, XB, dst, deg, pos,
                                             wb, xbk, n * 8, ecnt);
  const int nbk = (n + 4095) / 4096;
  k_scanA<<<nbk, 1024, 0, stream>>>(deg, rowptr, btot, dbins, n);
  k_scanB<<<1, 64, 0, stream>>>(btot, nbk, dbins, dcur);
  const int dblk = (n + 1023) / 1024;
  k_scanCD<<<dblk, 1024, 0, stream>>>(rowptr, btot, deg, dcur, order, n, nbk);
  k_fill<<<hbk, 256, 0, stream>>>(src, dst, rowptr, pos, adj, ecnt);

  const int pj = (n + 63) / 64;
  const int nb = (n + 31) / 32;   // 8 nodes/wave, 4 waves/block

  for (int l = 0; l < layers; ++l) {
    const size_t bo = (size_t)l * DD;
    k_projM<<<pj, 256, 0, stream>>>(XB, WF + (size_t)l * 16384,
                                    bq + bo, bk + bo, bv + bo, bs + bo,
                                    QH, KVH, SH, n);
    if (l == layers - 1)
      k_node<true><<<nb, 256, 0, stream>>>(QH, KVH, rowptr, adj, order,
                                           SH, out, XB, n);
    else
      k_node<false><<<nb, 256, 0, stream>>>(QH, KVH, rowptr, adj, order,
                                            SH, out, XB, n);
  }

  const int pbk = (n + 63) / 64;
  k_pool_sum<<<pbk, 64, 0, stream>>>(out, batch, gsum, n);
  const int fb = (gtot * DD + 255) / 256;
  k_pool_div<<<fb, 256, 0, stream>>>(gsum, batch, out + (size_t)nd, gtot, n);
}

// Round 14
// 332.253 us; speedup vs baseline: 1.2089x; 1.0068x over previous
//
#include <hip/hip_runtime.h>
#include <math.h>

#define DD 64    // feature dim
#define APAD 512 // adj zero-pad (branch-free over-read)
#define NCOPY 8  // privatized histogram copies

typedef _Float16 h2 __attribute__((ext_vector_type(2)));
typedef _Float16 h4 __attribute__((ext_vector_type(4)));
typedef _Float16 h8 __attribute__((ext_vector_type(8)));
typedef float f32x4 __attribute__((ext_vector_type(4)));

// ---- fused one-time prep: degree hist (privatized) | W frags | x->fp16 ----
// blocks [0,hb): hist; [hb,hb+wb): wconv; [hb+wb,...): xconv.
// hist goes FIRST so its atomic latency overlaps the streaming work.
__global__ __launch_bounds__(256) void k_prep(
    const float* __restrict__ Wq, const float* __restrict__ Wk,
    const float* __restrict__ Wv, const float* __restrict__ Ws,
    _Float16* __restrict__ wf,
    const float* __restrict__ x, _Float16* __restrict__ xb,
    const int* __restrict__ dst, int* __restrict__ degp,
    unsigned short* __restrict__ pos,
    int hb, int wb, int total8, int ecnt, int n)
{
  int tid = threadIdx.x;
  int bid = blockIdx.x;
  if (bid < hb) {
    const int c = bid & (NCOPY - 1);
    int* dp = degp + (size_t)c * n;
    const unsigned ctag = (unsigned)c << 13;
    int e = (bid * 256 + tid) * 4;
    if (e + 3 < ecnt) {
      int4 d = *(const int4*)(dst + e);
      unsigned s0 = atomicAdd(dp + d.x, 1);
      unsigned s1 = atomicAdd(dp + d.y, 1);
      unsigned s2 = atomicAdd(dp + d.z, 1);
      unsigned s3 = atomicAdd(dp + d.w, 1);
      ushort4 pv;
      pv.x = (unsigned short)(ctag | s0);
      pv.y = (unsigned short)(ctag | s1);
      pv.z = (unsigned short)(ctag | s2);
      pv.w = (unsigned short)(ctag | s3);
      *(ushort4*)(pos + e) = pv;
    } else {
      for (; e < ecnt; ++e)
        pos[e] = (unsigned short)(ctag | atomicAdd(dp + dst[e], 1));
    }
  } else if (bid < hb + wb) {
    int id = (bid - hb) * 4 + (tid >> 6);  // layer*32 + c*2 + s
    int lane = tid & 63;
    int layer = id >> 5;
    int c = (id >> 1) & 15;
    int s = id & 1;
    int col = c * 16 + (lane & 15);
    int mi = col >> 6;
    const float* W = (mi == 0 ? Wq : mi == 1 ? Wk : mi == 2 ? Wv : Ws)
                     + (size_t)layer * DD * DD;
    int colw = col & 63;
    _Float16* o = wf + ((((size_t)(layer * 16 + c)) * 2 + s) * 64 + lane) * 8;
    #pragma unroll
    for (int j = 0; j < 8; ++j) {
      int k = s * 32 + (lane >> 4) * 8 + j;
      o[j] = (_Float16)W[k * DD + colw];
    }
  } else {
    int i = (bid - hb - wb) * 256 + tid;
    if (i >= total8) return;
    float4 a = ((const float4*)x)[i * 2];
    float4 b = ((const float4*)x)[i * 2 + 1];
    h8 o;
    o[0] = (_Float16)a.x; o[1] = (_Float16)a.y; o[2] = (_Float16)a.z; o[3] = (_Float16)a.w;
    o[4] = (_Float16)b.x; o[5] = (_Float16)b.y; o[6] = (_Float16)b.z; o[7] = (_Float16)b.w;
    *(h8*)(xb + (size_t)i * 8) = o;
  }
}

// ---- MFMA projection, swapped operands + per-wave LDS staging ----
#define LH_STRIDE 200   // halves per node row (192 used + 8 pad) = 400B
#define LS_STRIDE 72    // halves per node row (64 used + 8 pad)  = 144B
#define WAVE_LDS  (16 * 400 + 16 * 144)   // 8704B

__global__ __launch_bounds__(256) void k_projM(
    const _Float16* __restrict__ xb, const _Float16* __restrict__ wf,
    const float* __restrict__ bq, const float* __restrict__ bk,
    const float* __restrict__ bv, const float* __restrict__ bs,
    _Float16* __restrict__ qh, _Float16* __restrict__ kvh,
    _Float16* __restrict__ sh, int n)
{
  __shared__ __align__(16) char lds[4 * WAVE_LDS];
  int wave = threadIdx.x >> 6;
  int lane = threadIdx.x & 63;
  int nbase = blockIdx.x * 64 + wave * 16;
  if (nbase >= n) return;

  char* wbase = lds + wave * WAVE_LDS;
  _Float16* lh = (_Float16*)wbase;                 // [16][LH_STRIDE] QKV
  _Float16* ls = (_Float16*)(wbase + 16 * 400);    // [16][LS_STRIDE] S

  const int cl = lane & 15;
  const int rq = lane >> 4;

  int ar = min(nbase + cl, n - 1);
  h8 a0 = *(const h8*)(xb + (size_t)ar * DD + rq * 8);
  h8 a1 = *(const h8*)(xb + (size_t)ar * DD + 32 + rq * 8);

  #pragma unroll
  for (int c = 0; c < 16; ++c) {
    const float* bp = (c < 4) ? bq : (c < 8) ? bk : (c < 12) ? bv : bs;
    const int fb = c * 16 + rq * 4;          // global feature base (0..255)
    float4 b4 = *(const float4*)(bp + (fb & 63));
    f32x4 acc; acc[0] = b4.x; acc[1] = b4.y; acc[2] = b4.z; acc[3] = b4.w;
    const _Float16* wp = wf + ((size_t)(c * 2) * 64 + lane) * 8;
    h8 w0 = *(const h8*)(wp);
    h8 w1 = *(const h8*)(wp + 64 * 8);
    acc = __builtin_amdgcn_mfma_f32_16x16x32_f16(w0, a0, acc, 0, 0, 0);
    acc = __builtin_amdgcn_mfma_f32_16x16x32_f16(w1, a1, acc, 0, 0, 0);

    h4 o; o[0] = (_Float16)acc[0]; o[1] = (_Float16)acc[1];
    o[2] = (_Float16)acc[2]; o[3] = (_Float16)acc[3];
    if (c < 12)
      *(h4*)(lh + cl * LH_STRIDE + fb) = o;
    else
      *(h4*)(ls + cl * LS_STRIDE + (fb - 192)) = o;
  }

  // QH: 16 nodes x 128B
  #pragma unroll
  for (int i = 0; i < 2; ++i) {
    int chunk = i * 64 + lane;
    int nd = chunk >> 3, co = chunk & 7;
    h8 v = *(const h8*)(lh + nd * LH_STRIDE + co * 8);
    if (nbase + nd < n)
      *(h8*)(qh + (size_t)(nbase + nd) * DD + co * 8) = v;
  }
  // KVH: 16 nodes x 256B
  #pragma unroll
  for (int i = 0; i < 4; ++i) {
    int chunk = i * 64 + lane;
    int nd = chunk >> 4, co = chunk & 15;
    h8 v = *(const h8*)(lh + nd * LH_STRIDE + 64 + co * 8);
    if (nbase + nd < n)
      *(h8*)(kvh + (size_t)(nbase + nd) * 128 + co * 8) = v;
  }
  // S: 16 nodes x 128B fp16
  #pragma unroll
  for (int i = 0; i < 2; ++i) {
    int chunk = i * 64 + lane;
    int nd = chunk >> 3, co = chunk & 7;
    h8 v = *(const h8*)(ls + nd * LS_STRIDE + co * 8);
    if (nbase + nd < n)
      *(h8*)(sh + (size_t)(nbase + nd) * DD + co * 8) = v;
  }
}

// ---- scan pass A: sum privatized copies -> totals + per-copy bases,
// block-local scan of totals, degree histogram for LPT binning ----
__global__ __launch_bounds__(1024) void k_scanA(
    const int* __restrict__ degp, int* __restrict__ basep,
    int* __restrict__ degt, int* __restrict__ rowptr,
    int* __restrict__ btot, int* __restrict__ dbins, int n)
{
  __shared__ int wsum[16];
  __shared__ int lbin[256];
  int tid = threadIdx.x;
  int lane = tid & 63, wave = tid >> 6;
  if (tid < 256) lbin[tid] = 0;
  __syncthreads();
  int i = blockIdx.x * 4096 + tid * 4;

  int4 t = make_int4(0, 0, 0, 0);
  if (i + 3 < n) {
    int4 run = make_int4(0, 0, 0, 0);
    #pragma unroll
    for (int x = 0; x < NCOPY; ++x) {
      int4 v = *(const int4*)(degp + (size_t)x * n + i);
      *(int4*)(basep + (size_t)x * n + i) = run;
      run.x += v.x; run.y += v.y; run.z += v.z; run.w += v.w;
    }
    t = run;
    *(int4*)(degt + i) = t;
  } else {
    for (int k = 0; k < 4; ++k) {
      int ii = i + k;
      if (ii < n) {
        int run = 0;
        #pragma unroll
        for (int x = 0; x < NCOPY; ++x) {
          int v = degp[(size_t)x * n + ii];
          basep[(size_t)x * n + ii] = run;
          run += v;
        }
        (&t.x)[k] = run;
        degt[ii] = run;
      }
    }
  }

  if (i     < n) atomicAdd(&lbin[min(t.x, 255)], 1);
  if (i + 1 < n) atomicAdd(&lbin[min(t.y, 255)], 1);
  if (i + 2 < n) atomicAdd(&lbin[min(t.z, 255)], 1);
  if (i + 3 < n) atomicAdd(&lbin[min(t.w, 255)], 1);

  int s1 = t.x, s2 = s1 + t.y, s3 = s2 + t.z, s4 = s3 + t.w;
  int s = s4;
  #pragma unroll
  for (int off = 1; off < 64; off <<= 1) {
    int tt = __shfl_up(s, off);
    if (lane >= off) s += tt;
  }
  if (lane == 63) wsum[wave] = s;
  __syncthreads();
  if (wave == 0) {
    int ws = (lane < 16) ? wsum[lane] : 0;
    #pragma unroll
    for (int off = 1; off < 16; off <<= 1) {
      int tt = __shfl_up(ws, off);
      if (lane >= off) ws += tt;
    }
    if (lane < 16) wsum[lane] = ws;
  }
  __syncthreads();
  int excl = ((wave > 0) ? wsum[wave - 1] : 0) + s - s4;
  if (i     < n) rowptr[i + 1] = excl + s1;
  if (i + 1 < n) rowptr[i + 2] = excl + s2;
  if (i + 2 < n) rowptr[i + 3] = excl + s3;
  if (i + 3 < n) rowptr[i + 4] = excl + s4;
  if (tid == 0) {
    if (blockIdx.x == 0) rowptr[0] = 0;
    btot[blockIdx.x] = wsum[15];
  }
  if (tid < 256 && lbin[tid]) atomicAdd(&dbins[tid], lbin[tid]);
}

// ---- pass B: exclusive-scan block totals (<=64) AND 256 degree bins ----
__global__ __launch_bounds__(64) void k_scanB(
    int* __restrict__ btot, int nb, const int* __restrict__ dbins,
    int* __restrict__ dcur)
{
  int lane = threadIdx.x;
  int v = (lane < nb) ? btot[lane] : 0;
  int s = v;
  #pragma unroll
  for (int off = 1; off < 64; off <<= 1) {
    int t = __shfl_up(s, off);
    if (lane >= off) s += t;
  }
  if (lane < nb) btot[lane] = s - v;

  int4 dv = *(const int4*)(dbins + lane * 4);
  int t1 = dv.x, t2 = t1 + dv.y, t3 = t2 + dv.z, t4 = t3 + dv.w;
  int ss = t4;
  #pragma unroll
  for (int off = 1; off < 64; off <<= 1) {
    int t = __shfl_up(ss, off);
    if (lane >= off) ss += t;
  }
  int ex = ss - t4;
  dcur[lane * 4]     = ex;
  dcur[lane * 4 + 1] = ex + t1;
  dcur[lane * 4 + 2] = ex + t2;
  dcur[lane * 4 + 3] = ex + t3;
}

// ---- fused pass C (+block offsets) and counting-sort scatter (LPT order) ----
__global__ __launch_bounds__(1024) void k_scanCD(
    int* __restrict__ rowptr, const int* __restrict__ btot,
    const int* __restrict__ degt, int* __restrict__ dcur,
    int* __restrict__ order, int n, int nbk)
{
  __shared__ int lcnt[256];
  __shared__ int lbase[256];
  int tid = threadIdx.x;
  int b = blockIdx.x;
  if (b < nbk) {                      // scanC chunk
    int off = btot[b];
    if (off) {
      int i = b * 4096 + tid * 4;
      #pragma unroll
      for (int k = 1; k <= 4; ++k)
        if (i + k <= n) rowptr[i + k] += off;
    }
  }
  // dfill chunk
  if (tid < 256) lcnt[tid] = 0;
  __syncthreads();
  int i = b * 1024 + tid;
  int bin = 0, slot = 0;
  bool ok = (i < n);
  if (ok) {
    bin = min(degt[i], 255);
    slot = atomicAdd(&lcnt[bin], 1);
  }
  __syncthreads();
  if (tid < 256 && lcnt[tid]) lbase[tid] = atomicAdd(&dcur[tid], lcnt[tid]);
  __syncthreads();
  if (ok) order[(n - 1) - (lbase[bin] + slot)] = i;   // reversed = descending
}

// atomic-free CSR fill: global slot = rowptr[d] + basep[copy][d] + slot
__global__ __launch_bounds__(256) void k_fill(
    const int* __restrict__ src, const int* __restrict__ dst,
    const int* __restrict__ rowptr, const int* __restrict__ basep,
    const unsigned short* __restrict__ pos,
    int* __restrict__ adj, int ecnt, int n)
{
  int e = (blockIdx.x * 256 + threadIdx.x) * 4;
  if (e + 3 < ecnt) {
    int4 d = *(const int4*)(dst + e);
    int4 s = *(const int4*)(src + e);
    ushort4 p = *(const ushort4*)(pos + e);
    adj[rowptr[d.x] + basep[(size_t)(p.x >> 13) * n + d.x] + (p.x & 8191)] = s.x;
    adj[rowptr[d.y] + basep[(size_t)(p.y >> 13) * n + d.y] + (p.y & 8191)] = s.y;
    adj[rowptr[d.z] + basep[(size_t)(p.z >> 13) * n + d.z] + (p.z & 8191)] = s.z;
    adj[rowptr[d.w] + basep[(size_t)(p.w >> 13) * n + d.w] + (p.w & 8191)] = s.w;
  } else {
    for (; e < ecnt; ++e) {
      int d = dst[e];
      unsigned short p = pos[e];
      adj[rowptr[d] + basep[(size_t)(p >> 13) * n + d] + (p & 8191)] = src[e];
    }
  }
}

#define H2OF(v, i) __builtin_shufflevector((v), (v), 2*(i), 2*(i)+1)

// ---- 8 nodes per wave, one 8-lane group per node (LPT degree order).
// Per-group loop (degree is group-uniform); exec mask handles divergence.
template<bool LAST>
__global__ __launch_bounds__(256) void k_node(
    const _Float16* __restrict__ qh, const _Float16* __restrict__ kvh,
    const int* __restrict__ rowptr, const int* __restrict__ adj,
    const int* __restrict__ order,
    const _Float16* __restrict__ sh, float* __restrict__ outp,
    _Float16* __restrict__ xbnext, int n)
{
  int wid = (blockIdx.x * blockDim.x + threadIdx.x) >> 6;
  int lane = threadIdx.x & 63;
  const int g = lane >> 3;   // node slot within wave
  const int t = lane & 7;    // dim-chunk (dims 8t..8t+7)

  int idx = wid * 8 + g;
  bool nok = (idx < n);
  int node = order[nok ? idx : (n - 1)];

  const h8 q8 = *(const h8*)(qh + (size_t)node * DD + t * 8);
  const h2 qp0 = H2OF(q8, 0), qp1 = H2OF(q8, 1), qp2 = H2OF(q8, 2), qp3 = H2OF(q8, 3);

  const int e0 = rowptr[node];
  const int d  = nok ? (rowptr[node + 1] - e0) : 0;

  float mg = -1e30f, den = 0.f;
  float agg[8] = {0.f, 0.f, 0.f, 0.f, 0.f, 0.f, 0.f, 0.f};

  const char* kvb = (const char*)kvh;
  const unsigned tb = (unsigned)t << 4;

  h8 kP, vP;
  {
    int s = adj[e0];                    // pad keeps this in-bounds
    unsigned off = ((unsigned)s << 8) + tb;
    kP = *(const h8*)(kvb + off);
    vP = *(const h8*)(kvb + off + 128);
  }

  for (int it = 0; it < d; ++it) {
    const h8 kc = kP, vc = vP;
    {                                   // prefetch next edge (over-reads pad)
      int s2 = adj[e0 + it + 1];
      unsigned off = ((unsigned)s2 << 8) + tb;
      kP = *(const h8*)(kvb + off);
      vP = *(const h8*)(kvb + off + 128);
    }

#if __has_builtin(__builtin_amdgcn_fdot2)
    float p = __builtin_amdgcn_fdot2(qp0, H2OF(kc, 0), 0.f, false);
    p = __builtin_amdgcn_fdot2(qp1, H2OF(kc, 1), p, false);
    p = __builtin_amdgcn_fdot2(qp2, H2OF(kc, 2), p, false);
    p = __builtin_amdgcn_fdot2(qp3, H2OF(kc, 3), p, false);
#else
    h2 ph = qp0 * H2OF(kc, 0);
    ph = qp1 * H2OF(kc, 1) + ph;
    ph = qp2 * H2OF(kc, 2) + ph;
    ph = qp3 * H2OF(kc, 3) + ph;
    float p = (float)ph.x + (float)ph.y;
#endif
    p += __shfl_xor(p, 1);
    p += __shfl_xor(p, 2);
    p += __shfl_xor(p, 4);     // p replicated within the 8-lane group
    p *= 0.125f;               // 1/sqrt(64)

    if (p > mg) {              // group-uniform; first iter rescales by 0
      float c = __expf(mg - p);
      den *= c;
      #pragma unroll
      for (int j = 0; j < 8; ++j) agg[j] *= c;
      mg = p;
    }
    float w = __expf(p - mg);
    den += w;
    #pragma unroll
    for (int j = 0; j < 8; ++j)
      agg[j] = fmaf(w, (float)vc[j], agg[j]);
  }

  if (nok) {
    float inv = (den > 0.f) ? (1.0f / den) : 0.f;
    const h8 s8 = *(const h8*)(sh + (size_t)node * DD + t * 8);
    float r[8];
    #pragma unroll
    for (int j = 0; j < 8; ++j)
      r[j] = fmaxf(fmaf(agg[j], inv, (float)s8[j]), 0.f);
    if (LAST) {
      float* op = outp + (size_t)node * DD + t * 8;
      *(float4*)(op)     = make_float4(r[0], r[1], r[2], r[3]);
      *(float4*)(op + 4) = make_float4(r[4], r[5], r[6], r[7]);
    } else {
      h8 xh;
      #pragma unroll
      for (int j = 0; j < 8; ++j) xh[j] = (_Float16)r[j];
      *(h8*)(xbnext + (size_t)node * DD + t * 8) = xh;
    }
  }
}

// batch is sorted: run-length accumulate per wave, flush on graph change
__global__ __launch_bounds__(64) void k_pool_sum(
    const float* __restrict__ x, const int* __restrict__ batch,
    float* __restrict__ gsum, int n)
{
  int lane = threadIdx.x;
  int n0 = blockIdx.x * 64;
  if (n0 >= n) return;
  int n1 = min(n0 + 64, n);
  float acc = 0.f;
  int g_prev = batch[n0];
  for (int nn = n0; nn < n1; ++nn) {
    int g = batch[nn];
    if (g != g_prev) {
      atomicAdd(gsum + (size_t)g_prev * DD + lane, acc);
      acc = 0.f; g_prev = g;
    }
    acc += x[(size_t)nn * DD + lane];
  }
  atomicAdd(gsum + (size_t)g_prev * DD + lane, acc);
}

__device__ __forceinline__ int lbound(const int* __restrict__ a, int n, int key)
{
  int lo = 0, hi = n;
  while (lo < hi) {
    int mid = (lo + hi) >> 1;
    if (a[mid] < key) lo = mid + 1; else hi = mid;
  }
  return lo;
}

// emb = gsum / count(g); counts via binary search on sorted batch
__global__ __launch_bounds__(256) void k_pool_div(
    const float* __restrict__ gsum, const int* __restrict__ batch,
    float* __restrict__ emb, int gtot, int n)
{
  int gid = blockIdx.x * blockDim.x + threadIdx.x;
  if (gid >= gtot * DD) return;
  int g = gid >> 6;
  int cnt = lbound(batch, n, g + 1) - lbound(batch, n, g);
  emb[gid] = gsum[gid] / fmaxf((float)cnt, 1.0f);
}

extern "C" void kernel_launch(void* const* d_in, const int* in_sizes, int n_in,
                              void* d_out, int out_size, void* d_ws, size_t ws_size,
                              hipStream_t stream)
{
  const float* x_in  = (const float*)d_in[0];
  const int*   ei    = (const int*)  d_in[1];
  const int*   batch = (const int*)  d_in[2];
  const float* Wq = (const float*)d_in[3];
  const float* bq = (const float*)d_in[4];
  const float* Wk = (const float*)d_in[5];
  const float* bk = (const float*)d_in[6];
  const float* Wv = (const float*)d_in[7];
  const float* bv = (const float*)d_in[8];
  const float* Ws = (const float*)d_in[9];
  const float* bs = (const float*)d_in[10];

  const int nd     = in_sizes[0];             // N*D
  const int n      = nd / DD;                 // N
  const int ecnt   = in_sizes[1] / 2;         // E
  const int layers = in_sizes[3] / (DD * DD); // L
  const int gtot   = (out_size - nd) / DD;    // G

  const int* src = ei;
  const int* dst = ei + ecnt;

  // workspace layout: adj pad, degp, dbins, gsum contiguous -> ONE memset
  char* cur = (char*)d_ws;
  _Float16*  SH  = (_Float16*)cur;  cur += (size_t)nd * 2;        // fp16 skip S
  _Float16*  XB  = (_Float16*)cur;  cur += (size_t)nd * 2;        // fp16 x
  _Float16*  QH  = (_Float16*)cur;  cur += (size_t)nd * 2;        // fp16 Q
  _Float16*  KVH = (_Float16*)cur;  cur += (size_t)nd * 4;        // fp16 K|V
  _Float16*  WF  = (_Float16*)cur;  cur += (size_t)layers * 16384 * 2; // W frags
  int* rowptr = (int*)cur;          cur += (size_t)(n + 4) * 4;
  int* adj    = (int*)cur;          cur += (size_t)(ecnt + APAD) * 4;
  int* degp   = (int*)cur;          cur += (size_t)NCOPY * n * 4;  // zeroed
  int* dbins  = (int*)cur;          cur += 256 * 4;                // zeroed
  float* gsum = (float*)cur;        cur += (size_t)gtot * DD * 4;  // zeroed
  int* basep  = (int*)cur;          cur += (size_t)NCOPY * n * 4;
  int* degt   = (int*)cur;          cur += (size_t)n * 4;
  int* dcur   = (int*)cur;          cur += 256 * 4;
  int* btot   = (int*)cur;          cur += 64 * 4;
  int* order  = (int*)cur;          cur += (size_t)n * 4;
  unsigned short* pos = (unsigned short*)cur; cur += (size_t)ecnt * 2;

  float* out = (float*)d_out;

  // ---- one memset covers adj pad + degp + dbins + gsum ----
  hipMemsetAsync(adj + ecnt, 0,
                 (size_t)(APAD + NCOPY * n + 256 + gtot * DD) * 4, stream);

  // ---- fused prep: hist (privatized) | W frags | x fp16 ----
  const int hbk = (ecnt + 1023) / 1024;
  const int wb  = layers * 8;
  const int xbk = (n * 8 + 255) / 256;
  k_prep<<<hbk + wb + xbk, 256, 0, stream>>>(Wq, Wk, Wv, Ws, WF,
                                             x_in, XB, dst, degp, pos,
                                             hbk, wb, n * 8, ecnt, n);
  const int nbk = (n + 4095) / 4096;
  k_scanA<<<nbk, 1024, 0, stream>>>(degp, basep, degt, rowptr, btot, dbins, n);
  k_scanB<<<1, 64, 0, stream>>>(btot, nbk, dbins, dcur);
  const int dblk = (n + 1023) / 1024;
  k_scanCD<<<dblk, 1024, 0, stream>>>(rowptr, btot, degt, dcur, order, n, nbk);
  k_fill<<<hbk, 256, 0, stream>>>(src, dst, rowptr, basep, pos, adj, ecnt, n);

  const int pj = (n + 63) / 64;
  const int nb = (n + 31) / 32;   // 8 nodes/wave, 4 waves/block

  for (int l = 0; l < layers; ++l) {
    const size_t bo = (size_t)l * DD;
    k_projM<<<pj, 256, 0, stream>>>(XB, WF + (size_t)l * 16384,
                                    bq + bo, bk + bo, bv + bo, bs + bo,
                                    QH, KVH, SH, n);
    if (l == layers - 1)
      k_node<true><<<nb, 256, 0, stream>>>(QH, KVH, rowptr, adj, order,
                                           SH, out, XB, n);
    else
      k_node<false><<<nb, 256, 0, stream>>>(QH, KVH, rowptr, adj, order,
                                            SH, out, XB, n);
  }

  const int pbk = (n + 63) / 64;
  k_pool_sum<<<pbk, 64, 0, stream>>>(out, batch, gsum, n);
  const int fb = (gtot * DD + 255) / 256;
  k_pool_div<<<fb, 256, 0, stream>>>(gsum, batch, out + (size_t)nd, gtot, n);
}

// Round 15
// 322.249 us; speedup vs baseline: 1.2464x; 1.0310x over previous
//
#include <hip/hip_runtime.h>
#include <math.h>

#define DD 64    // feature dim
#define APAD 512 // adj zero-pad (branch-free over-read)

typedef _Float16 h2 __attribute__((ext_vector_type(2)));
typedef _Float16 h4 __attribute__((ext_vector_type(4)));
typedef _Float16 h8 __attribute__((ext_vector_type(8)));
typedef float f32x4 __attribute__((ext_vector_type(4)));

// ---- standalone degree histogram (returns slot in pos) ----
// Runs ALONE so the 400KB deg working set stays L2-resident (no streaming
// traffic evicting dirty atomic lines).
__global__ __launch_bounds__(256) void k_hist(
    const int* __restrict__ dst, int* __restrict__ deg,
    unsigned short* __restrict__ pos, int ecnt)
{
  int e = (blockIdx.x * 256 + threadIdx.x) * 4;
  if (e + 3 < ecnt) {
    int4 d = *(const int4*)(dst + e);
    ushort4 pv;
    pv.x = (unsigned short)atomicAdd(deg + d.x, 1);
    pv.y = (unsigned short)atomicAdd(deg + d.y, 1);
    pv.z = (unsigned short)atomicAdd(deg + d.z, 1);
    pv.w = (unsigned short)atomicAdd(deg + d.w, 1);
    *(ushort4*)(pos + e) = pv;
  } else {
    for (; e < ecnt; ++e)
      pos[e] = (unsigned short)atomicAdd(deg + dst[e], 1);
  }
}

// ---- fused: scanA-blocks | wconv | xconv  (all depend only on k_hist) ----
// blocks [0,nbk): scanA (1024 nodes/block, 256 thr x 4);
// [nbk,nbk+wb): wconv; rest: xconv.
__global__ __launch_bounds__(256) void k_mix(
    const float* __restrict__ Wq, const float* __restrict__ Wk,
    const float* __restrict__ Wv, const float* __restrict__ Ws,
    _Float16* __restrict__ wf,
    const float* __restrict__ x, _Float16* __restrict__ xb,
    const int* __restrict__ deg, int* __restrict__ rowptr,
    int* __restrict__ btot, int* __restrict__ dbins,
    int nbk, int wb, int total8, int n)
{
  int tid = threadIdx.x;
  int bid = blockIdx.x;
  if (bid < nbk) {                      // ---- scanA ----
    __shared__ int wsum[4];
    __shared__ int lbin[256];
    int lane = tid & 63, wave = tid >> 6;
    lbin[tid] = 0;
    __syncthreads();
    int i = bid * 1024 + tid * 4;
    int4 d = make_int4(0, 0, 0, 0);
    if (i + 3 < n) d = *(const int4*)(deg + i);
    else {
      if (i     < n) d.x = deg[i];
      if (i + 1 < n) d.y = deg[i + 1];
      if (i + 2 < n) d.z = deg[i + 2];
    }
    if (i     < n) atomicAdd(&lbin[min(d.x, 255)], 1);
    if (i + 1 < n) atomicAdd(&lbin[min(d.y, 255)], 1);
    if (i + 2 < n) atomicAdd(&lbin[min(d.z, 255)], 1);
    if (i + 3 < n) atomicAdd(&lbin[min(d.w, 255)], 1);

    int s1 = d.x, s2 = s1 + d.y, s3 = s2 + d.z, s4 = s3 + d.w;
    int s = s4;
    #pragma unroll
    for (int off = 1; off < 64; off <<= 1) {
      int t = __shfl_up(s, off);
      if (lane >= off) s += t;
    }
    if (lane == 63) wsum[wave] = s;
    __syncthreads();
    if (wave == 0) {
      int ws = (lane < 4) ? wsum[lane] : 0;
      #pragma unroll
      for (int off = 1; off < 4; off <<= 1) {
        int t = __shfl_up(ws, off);
        if (lane >= off) ws += t;
      }
      if (lane < 4) wsum[lane] = ws;
    }
    __syncthreads();
    int excl = ((wave > 0) ? wsum[wave - 1] : 0) + s - s4;
    if (i     < n) rowptr[i + 1] = excl + s1;
    if (i + 1 < n) rowptr[i + 2] = excl + s2;
    if (i + 2 < n) rowptr[i + 3] = excl + s3;
    if (i + 3 < n) rowptr[i + 4] = excl + s4;
    if (tid == 0) {
      if (bid == 0) rowptr[0] = 0;
      btot[bid] = wsum[3];
    }
    if (lbin[tid]) atomicAdd(&dbins[tid], lbin[tid]);
  } else if (bid < nbk + wb) {          // ---- wconv ----
    int id = (bid - nbk) * 4 + (tid >> 6);  // layer*32 + c*2 + s
    int lane = tid & 63;
    int layer = id >> 5;
    int c = (id >> 1) & 15;
    int s = id & 1;
    int col = c * 16 + (lane & 15);
    int mi = col >> 6;
    const float* W = (mi == 0 ? Wq : mi == 1 ? Wk : mi == 2 ? Wv : Ws)
                     + (size_t)layer * DD * DD;
    int colw = col & 63;
    _Float16* o = wf + ((((size_t)(layer * 16 + c)) * 2 + s) * 64 + lane) * 8;
    #pragma unroll
    for (int j = 0; j < 8; ++j) {
      int k = s * 32 + (lane >> 4) * 8 + j;
      o[j] = (_Float16)W[k * DD + colw];
    }
  } else {                              // ---- xconv ----
    int i = (bid - nbk - wb) * 256 + tid;
    if (i >= total8) return;
    float4 a = ((const float4*)x)[i * 2];
    float4 b = ((const float4*)x)[i * 2 + 1];
    h8 o;
    o[0] = (_Float16)a.x; o[1] = (_Float16)a.y; o[2] = (_Float16)a.z; o[3] = (_Float16)a.w;
    o[4] = (_Float16)b.x; o[5] = (_Float16)b.y; o[6] = (_Float16)b.z; o[7] = (_Float16)b.w;
    *(h8*)(xb + (size_t)i * 8) = o;
  }
}

// ---- pass B: exclusive-scan block totals (<=128) AND 256 degree bins ----
__global__ __launch_bounds__(64) void k_scanB(
    int* __restrict__ btot, int nb, const int* __restrict__ dbins,
    int* __restrict__ dcur)
{
  int lane = threadIdx.x;
  int v0 = (lane < nb) ? btot[lane] : 0;
  int v1 = (64 + lane < nb) ? btot[64 + lane] : 0;
  int s0 = v0;
  #pragma unroll
  for (int off = 1; off < 64; off <<= 1) {
    int t = __shfl_up(s0, off);
    if (lane >= off) s0 += t;
  }
  int tot0 = __shfl(s0, 63);
  int s1 = v1;
  #pragma unroll
  for (int off = 1; off < 64; off <<= 1) {
    int t = __shfl_up(s1, off);
    if (lane >= off) s1 += t;
  }
  if (lane < nb) btot[lane] = s0 - v0;
  if (64 + lane < nb) btot[64 + lane] = tot0 + s1 - v1;

  int4 dv = *(const int4*)(dbins + lane * 4);
  int t1 = dv.x, t2 = t1 + dv.y, t3 = t2 + dv.z, t4 = t3 + dv.w;
  int ss = t4;
  #pragma unroll
  for (int off = 1; off < 64; off <<= 1) {
    int t = __shfl_up(ss, off);
    if (lane >= off) ss += t;
  }
  int ex = ss - t4;
  dcur[lane * 4]     = ex;
  dcur[lane * 4 + 1] = ex + t1;
  dcur[lane * 4 + 2] = ex + t2;
  dcur[lane * 4 + 3] = ex + t3;
}

// ---- fused pass C (+block offsets) and counting-sort scatter (LPT order) ----
// nbk blocks x 1024 threads; block b owns nodes [b*1024, b*1024+1024)
__global__ __launch_bounds__(1024) void k_scanCD(
    int* __restrict__ rowptr, const int* __restrict__ btot,
    const int* __restrict__ deg, int* __restrict__ dcur,
    int* __restrict__ order, int n)
{
  __shared__ int lcnt[256];
  __shared__ int lbase[256];
  int tid = threadIdx.x;
  int b = blockIdx.x;
  int off = btot[b];
  int i = b * 1024 + tid;
  if (off && i < n) rowptr[i + 1] += off;
  if (tid < 256) lcnt[tid] = 0;
  __syncthreads();
  int bin = 0, slot = 0;
  bool ok = (i < n);
  if (ok) {
    bin = min(deg[i], 255);
    slot = atomicAdd(&lcnt[bin], 1);
  }
  __syncthreads();
  if (tid < 256 && lcnt[tid]) lbase[tid] = atomicAdd(&dcur[tid], lcnt[tid]);
  __syncthreads();
  if (ok) order[(n - 1) - (lbase[bin] + slot)] = i;   // reversed = descending
}

// ---- shared projM body (swapped-operand MFMA + per-wave LDS staging) ----
#define LH_STRIDE 200   // halves per node row (192 used + 8 pad) = 400B
#define LS_STRIDE 72    // halves per node row (64 used + 8 pad)  = 144B
#define WAVE_LDS  (16 * 400 + 16 * 144)   // 8704B

__device__ __forceinline__ void projM_body(
    int blk, int tid, char* lds,
    const _Float16* __restrict__ xb, const _Float16* __restrict__ wf,
    const float* __restrict__ bq, const float* __restrict__ bk,
    const float* __restrict__ bv, const float* __restrict__ bs,
    _Float16* __restrict__ qh, _Float16* __restrict__ kvh,
    _Float16* __restrict__ sh, int n)
{
  int wave = tid >> 6;
  int lane = tid & 63;
  int nbase = blk * 64 + wave * 16;
  if (nbase >= n) return;

  char* wbase = lds + wave * WAVE_LDS;
  _Float16* lh = (_Float16*)wbase;                 // [16][LH_STRIDE] QKV
  _Float16* ls = (_Float16*)(wbase + 16 * 400);    // [16][LS_STRIDE] S

  const int cl = lane & 15;
  const int rq = lane >> 4;

  int ar = min(nbase + cl, n - 1);
  h8 a0 = *(const h8*)(xb + (size_t)ar * DD + rq * 8);
  h8 a1 = *(const h8*)(xb + (size_t)ar * DD + 32 + rq * 8);

  #pragma unroll
  for (int c = 0; c < 16; ++c) {
    const float* bp = (c < 4) ? bq : (c < 8) ? bk : (c < 12) ? bv : bs;
    const int fb = c * 16 + rq * 4;          // global feature base (0..255)
    float4 b4 = *(const float4*)(bp + (fb & 63));
    f32x4 acc; acc[0] = b4.x; acc[1] = b4.y; acc[2] = b4.z; acc[3] = b4.w;
    const _Float16* wp = wf + ((size_t)(c * 2) * 64 + lane) * 8;
    h8 w0 = *(const h8*)(wp);
    h8 w1 = *(const h8*)(wp + 64 * 8);
    acc = __builtin_amdgcn_mfma_f32_16x16x32_f16(w0, a0, acc, 0, 0, 0);
    acc = __builtin_amdgcn_mfma_f32_16x16x32_f16(w1, a1, acc, 0, 0, 0);

    h4 o; o[0] = (_Float16)acc[0]; o[1] = (_Float16)acc[1];
    o[2] = (_Float16)acc[2]; o[3] = (_Float16)acc[3];
    if (c < 12)
      *(h4*)(lh + cl * LH_STRIDE + fb) = o;
    else
      *(h4*)(ls + cl * LS_STRIDE + (fb - 192)) = o;
  }

  // QH: 16 nodes x 128B
  #pragma unroll
  for (int i = 0; i < 2; ++i) {
    int chunk = i * 64 + lane;
    int nd = chunk >> 3, co = chunk & 7;
    h8 v = *(const h8*)(lh + nd * LH_STRIDE + co * 8);
    if (nbase + nd < n)
      *(h8*)(qh + (size_t)(nbase + nd) * DD + co * 8) = v;
  }
  // KVH: 16 nodes x 256B
  #pragma unroll
  for (int i = 0; i < 4; ++i) {
    int chunk = i * 64 + lane;
    int nd = chunk >> 4, co = chunk & 15;
    h8 v = *(const h8*)(lh + nd * LH_STRIDE + 64 + co * 8);
    if (nbase + nd < n)
      *(h8*)(kvh + (size_t)(nbase + nd) * 128 + co * 8) = v;
  }
  // S: 16 nodes x 128B fp16
  #pragma unroll
  for (int i = 0; i < 2; ++i) {
    int chunk = i * 64 + lane;
    int nd = chunk >> 3, co = chunk & 7;
    h8 v = *(const h8*)(ls + nd * LS_STRIDE + co * 8);
    if (nbase + nd < n)
      *(h8*)(sh + (size_t)(nbase + nd) * DD + co * 8) = v;
  }
}

__global__ __launch_bounds__(256) void k_projM(
    const _Float16* __restrict__ xb, const _Float16* __restrict__ wf,
    const float* __restrict__ bq, const float* __restrict__ bk,
    const float* __restrict__ bv, const float* __restrict__ bs,
    _Float16* __restrict__ qh, _Float16* __restrict__ kvh,
    _Float16* __restrict__ sh, int n)
{
  __shared__ __align__(16) char lds[4 * WAVE_LDS];
  projM_body(blockIdx.x, threadIdx.x, lds, xb, wf, bq, bk, bv, bs,
             qh, kvh, sh, n);
}

// ---- fused: CSR fill | projM layer 0 (independent; both precede node0) ----
__global__ __launch_bounds__(256) void k_fillproj(
    const int* __restrict__ src, const int* __restrict__ dst,
    const int* __restrict__ rowptr, const unsigned short* __restrict__ pos,
    int* __restrict__ adj, int ecnt, int hbk,
    const _Float16* __restrict__ xb, const _Float16* __restrict__ wf,
    const float* __restrict__ bq, const float* __restrict__ bk,
    const float* __restrict__ bv, const float* __restrict__ bs,
    _Float16* __restrict__ qh, _Float16* __restrict__ kvh,
    _Float16* __restrict__ sh, int n)
{
  __shared__ __align__(16) char lds[4 * WAVE_LDS];
  int bid = blockIdx.x;
  if (bid < hbk) {                       // ---- fill ----
    int e = (bid * 256 + threadIdx.x) * 4;
    if (e + 3 < ecnt) {
      int4 d = *(const int4*)(dst + e);
      int4 s = *(const int4*)(src + e);
      ushort4 p = *(const ushort4*)(pos + e);
      adj[rowptr[d.x] + p.x] = s.x;
      adj[rowptr[d.y] + p.y] = s.y;
      adj[rowptr[d.z] + p.z] = s.z;
      adj[rowptr[d.w] + p.w] = s.w;
    } else {
      for (; e < ecnt; ++e)
        adj[rowptr[dst[e]] + pos[e]] = src[e];
    }
  } else {                               // ---- projM layer 0 ----
    projM_body(bid - hbk, threadIdx.x, lds, xb, wf, bq, bk, bv, bs,
               qh, kvh, sh, n);
  }
}

#define H2OF(v, i) __builtin_shufflevector((v), (v), 2*(i), 2*(i)+1)

// ---- 8 nodes per wave, one 8-lane group per node (LPT degree order).
// Per-group loop (degree is group-uniform); exec mask handles divergence.
template<bool LAST>
__global__ __launch_bounds__(256) void k_node(
    const _Float16* __restrict__ qh, const _Float16* __restrict__ kvh,
    const int* __restrict__ rowptr, const int* __restrict__ adj,
    const int* __restrict__ order,
    const _Float16* __restrict__ sh, float* __restrict__ outp,
    _Float16* __restrict__ xbnext, int n)
{
  int wid = (blockIdx.x * blockDim.x + threadIdx.x) >> 6;
  int lane = threadIdx.x & 63;
  const int g = lane >> 3;   // node slot within wave
  const int t = lane & 7;    // dim-chunk (dims 8t..8t+7)

  int idx = wid * 8 + g;
  bool nok = (idx < n);
  int node = order[nok ? idx : (n - 1)];

  const h8 q8 = *(const h8*)(qh + (size_t)node * DD + t * 8);
  const h2 qp0 = H2OF(q8, 0), qp1 = H2OF(q8, 1), qp2 = H2OF(q8, 2), qp3 = H2OF(q8, 3);

  const int e0 = rowptr[node];
  const int d  = nok ? (rowptr[node + 1] - e0) : 0;

  float mg = -1e30f, den = 0.f;
  float agg[8] = {0.f, 0.f, 0.f, 0.f, 0.f, 0.f, 0.f, 0.f};

  const char* kvb = (const char*)kvh;
  const unsigned tb = (unsigned)t << 4;

  h8 kP, vP;
  {
    int s = adj[e0];                    // pad keeps this in-bounds
    unsigned off = ((unsigned)s << 8) + tb;
    kP = *(const h8*)(kvb + off);
    vP = *(const h8*)(kvb + off + 128);
  }

  for (int it = 0; it < d; ++it) {
    const h8 kc = kP, vc = vP;
    {                                   // prefetch next edge (over-reads pad)
      int s2 = adj[e0 + it + 1];
      unsigned off = ((unsigned)s2 << 8) + tb;
      kP = *(const h8*)(kvb + off);
      vP = *(const h8*)(kvb + off + 128);
    }

#if __has_builtin(__builtin_amdgcn_fdot2)
    float p = __builtin_amdgcn_fdot2(qp0, H2OF(kc, 0), 0.f, false);
    p = __builtin_amdgcn_fdot2(qp1, H2OF(kc, 1), p, false);
    p = __builtin_amdgcn_fdot2(qp2, H2OF(kc, 2), p, false);
    p = __builtin_amdgcn_fdot2(qp3, H2OF(kc, 3), p, false);
#else
    h2 ph = qp0 * H2OF(kc, 0);
    ph = qp1 * H2OF(kc, 1) + ph;
    ph = qp2 * H2OF(kc, 2) + ph;
    ph = qp3 * H2OF(kc, 3) + ph;
    float p = (float)ph.x + (float)ph.y;
#endif
    p += __shfl_xor(p, 1);
    p += __shfl_xor(p, 2);
    p += __shfl_xor(p, 4);     // p replicated within the 8-lane group
    p *= 0.125f;               // 1/sqrt(64)

    if (p > mg) {              // group-uniform; first iter rescales by 0
      float c = __expf(mg - p);
      den *= c;
      #pragma unroll
      for (int j = 0; j < 8; ++j) agg[j] *= c;
      mg = p;
    }
    float w = __expf(p - mg);
    den += w;
    #pragma unroll
    for (int j = 0; j < 8; ++j)
      agg[j] = fmaf(w, (float)vc[j], agg[j]);
  }

  if (nok) {
    float inv = (den > 0.f) ? (1.0f / den) : 0.f;
    const h8 s8 = *(const h8*)(sh + (size_t)node * DD + t * 8);
    float r[8];
    #pragma unroll
    for (int j = 0; j < 8; ++j)
      r[j] = fmaxf(fmaf(agg[j], inv, (float)s8[j]), 0.f);
    if (LAST) {
      float* op = outp + (size_t)node * DD + t * 8;
      *(float4*)(op)     = make_float4(r[0], r[1], r[2], r[3]);
      *(float4*)(op + 4) = make_float4(r[4], r[5], r[6], r[7]);
    } else {
      h8 xh;
      #pragma unroll
      for (int j = 0; j < 8; ++j) xh[j] = (_Float16)r[j];
      *(h8*)(xbnext + (size_t)node * DD + t * 8) = xh;
    }
  }
}

// batch is sorted: run-length accumulate per wave, flush on graph change
__global__ __launch_bounds__(64) void k_pool_sum(
    const float* __restrict__ x, const int* __restrict__ batch,
    float* __restrict__ gsum, int n)
{
  int lane = threadIdx.x;
  int n0 = blockIdx.x * 64;
  if (n0 >= n) return;
  int n1 = min(n0 + 64, n);
  float acc = 0.f;
  int g_prev = batch[n0];
  for (int nn = n0; nn < n1; ++nn) {
    int g = batch[nn];
    if (g != g_prev) {
      atomicAdd(gsum + (size_t)g_prev * DD + lane, acc);
      acc = 0.f; g_prev = g;
    }
    acc += x[(size_t)nn * DD + lane];
  }
  atomicAdd(gsum + (size_t)g_prev * DD + lane, acc);
}

__device__ __forceinline__ int lbound(const int* __restrict__ a, int n, int key)
{
  int lo = 0, hi = n;
  while (lo < hi) {
    int mid = (lo + hi) >> 1;
    if (a[mid] < key) lo = mid + 1; else hi = mid;
  }
  return lo;
}

// emb = gsum / count(g); counts via binary search on sorted batch
__global__ __launch_bounds__(256) void k_pool_div(
    const float* __restrict__ gsum, const int* __restrict__ batch,
    float* __restrict__ emb, int gtot, int n)
{
  int gid = blockIdx.x * blockDim.x + threadIdx.x;
  if (gid >= gtot * DD) return;
  int g = gid >> 6;
  int cnt = lbound(batch, n, g + 1) - lbound(batch, n, g);
  emb[gid] = gsum[gid] / fmaxf((float)cnt, 1.0f);
}

extern "C" void kernel_launch(void* const* d_in, const int* in_sizes, int n_in,
                              void* d_out, int out_size, void* d_ws, size_t ws_size,
                              hipStream_t stream)
{
  const float* x_in  = (const float*)d_in[0];
  const int*   ei    = (const int*)  d_in[1];
  const int*   batch = (const int*)  d_in[2];
  const float* Wq = (const float*)d_in[3];
  const float* bq = (const float*)d_in[4];
  const float* Wk = (const float*)d_in[5];
  const float* bk = (const float*)d_in[6];
  const float* Wv = (const float*)d_in[7];
  const float* bv = (const float*)d_in[8];
  const float* Ws = (const float*)d_in[9];
  const float* bs = (const float*)d_in[10];

  const int nd     = in_sizes[0];             // N*D
  const int n      = nd / DD;                 // N
  const int ecnt   = in_sizes[1] / 2;         // E
  const int layers = in_sizes[3] / (DD * DD); // L
  const int gtot   = (out_size - nd) / DD;    // G

  const int* src = ei;
  const int* dst = ei + ecnt;

  // workspace layout: adj pad, deg, dbins, gsum contiguous -> ONE memset
  char* cur = (char*)d_ws;
  _Float16*  SH  = (_Float16*)cur;  cur += (size_t)nd * 2;        // fp16 skip S
  _Float16*  XB  = (_Float16*)cur;  cur += (size_t)nd * 2;        // fp16 x
  _Float16*  QH  = (_Float16*)cur;  cur += (size_t)nd * 2;        // fp16 Q
  _Float16*  KVH = (_Float16*)cur;  cur += (size_t)nd * 4;        // fp16 K|V
  _Float16*  WF  = (_Float16*)cur;  cur += (size_t)layers * 16384 * 2; // W frags
  int* rowptr = (int*)cur;          cur += (size_t)(n + 4) * 4;
  int* adj    = (int*)cur;          cur += (size_t)(ecnt + APAD) * 4;
  int* deg    = (int*)cur;          cur += (size_t)n * 4;          // zeroed
  int* dbins  = (int*)cur;          cur += 256 * 4;                // zeroed
  float* gsum = (float*)cur;        cur += (size_t)gtot * DD * 4;  // zeroed
  int* dcur   = (int*)cur;          cur += 256 * 4;
  int* btot   = (int*)cur;          cur += 128 * 4;
  int* order  = (int*)cur;          cur += (size_t)n * 4;
  unsigned short* pos = (unsigned short*)cur; cur += (size_t)ecnt * 2;

  float* out = (float*)d_out;

  // ---- one memset covers adj pad + deg + dbins + gsum ----
  hipMemsetAsync(adj + ecnt, 0,
                 (size_t)(APAD + n + 256 + gtot * DD) * 4, stream);

  const int hbk = (ecnt + 1023) / 1024;
  const int nbk = (n + 1023) / 1024;        // <=128 (scanB capacity)
  const int wb  = layers * 8;
  const int xbk = (n * 8 + 255) / 256;
  const int pj  = (n + 63) / 64;
  const int nb  = (n + 31) / 32;            // 8 nodes/wave, 4 waves/block

  // ---- CSR + prep chain ----
  k_hist<<<hbk, 256, 0, stream>>>(dst, deg, pos, ecnt);
  k_mix<<<nbk + wb + xbk, 256, 0, stream>>>(Wq, Wk, Wv, Ws, WF, x_in, XB,
                                            deg, rowptr, btot, dbins,
                                            nbk, wb, n * 8, n);
  k_scanB<<<1, 64, 0, stream>>>(btot, nbk, dbins, dcur);
  k_scanCD<<<nbk, 1024, 0, stream>>>(rowptr, btot, deg, dcur, order, n);

  // ---- fill | projM layer 0 (fused), then layer loop ----
  k_fillproj<<<hbk + pj, 256, 0, stream>>>(src, dst, rowptr, pos, adj, ecnt,
                                           hbk, XB, WF, bq, bk, bv, bs,
                                           QH, KVH, SH, n);
  for (int l = 0; l < layers; ++l) {
    if (l > 0) {
      const size_t bo = (size_t)l * DD;
      k_projM<<<pj, 256, 0, stream>>>(XB, WF + (size_t)l * 16384,
                                      bq + bo, bk + bo, bv + bo, bs + bo,
                                      QH, KVH, SH, n);
    }
    if (l == layers - 1)
      k_node<true><<<nb, 256, 0, stream>>>(QH, KVH, rowptr, adj, order,
                                           SH, out, XB, n);
    else
      k_node<false><<<nb, 256, 0, stream>>>(QH, KVH, rowptr, adj, order,
                                            SH, out, XB, n);
  }

  const int pbk = (n + 63) / 64;
  k_pool_sum<<<pbk, 64, 0, stream>>>(out, batch, gsum, n);
  const int fb = (gtot * DD + 255) / 256;
  k_pool_div<<<fb, 256, 0, stream>>>(gsum, batch, out + (size_t)nd, gtot, n);
}